// Round 5
// baseline (269.899 us; speedup 1.0000x reference)
//
#include <hip/hip_runtime.h>
#include <hip/hip_bf16.h>
#include <math.h>

#define N_EMBD 768
#define N_HEAD 12
#define BATCH  2
#define SEQ    2048
#define ROWS   (BATCH*SEQ)   // 4096
#define C3     (3*N_EMBD)    // 2304

typedef __bf16 bf16;
typedef __attribute__((ext_vector_type(8))) __bf16 bf16x8;
typedef __attribute__((ext_vector_type(4))) float f32x4;

// async global->LDS, 16B per lane. LDS dest must be wave-uniform base + 16*lane.
__device__ __forceinline__ void async16(const bf16* g, bf16* l) {
    __builtin_amdgcn_global_load_lds(
        (const __attribute__((address_space(1))) uint32_t*)g,
        (__attribute__((address_space(3))) uint32_t*)l, 16, 0, 0);
}

// ---------------- merged transpose+cast for all 4 weights: in[K,N] -> out[N,K] ----------------
__global__ __launch_bounds__(256) void k_transpose_all(
    const float* __restrict__ w0, bf16* __restrict__ o0,   // attn K=768  N=2304 (1728 tiles)
    const float* __restrict__ w1, bf16* __restrict__ o1,   // proj K=768  N=768  (576)
    const float* __restrict__ w2, bf16* __restrict__ o2,   // fc   K=768  N=3072 (2304)
    const float* __restrict__ w3, bf16* __restrict__ o3)   // mlp  K=3072 N=768  (2304)
{
    __shared__ bf16 tile[32][33];
    int bid = blockIdx.x;
    const float* in; bf16* out; int K, N, local;
    if      (bid < 1728) { in = w0; out = o0; K = 768;  N = 2304; local = bid; }
    else if (bid < 2304) { in = w1; out = o1; K = 768;  N = 768;  local = bid - 1728; }
    else if (bid < 4608) { in = w2; out = o2; K = 768;  N = 3072; local = bid - 2304; }
    else                 { in = w3; out = o3; K = 3072; N = 768;  local = bid - 4608; }
    int nt = N / 32;
    int n0 = (local % nt) * 32, k0 = (local / nt) * 32;
    int tc = threadIdx.x & 31, tr = threadIdx.x >> 5;
    #pragma unroll
    for (int i = 0; i < 4; i++) {
        int r = tr + i * 8;
        tile[r][tc] = (bf16)in[(size_t)(k0 + r) * N + n0 + tc];
    }
    __syncthreads();
    #pragma unroll
    for (int i = 0; i < 4; i++) {
        int r = tr + i * 8;
        out[(size_t)(n0 + r) * K + k0 + tc] = tile[tc][r];
    }
}

// ---------------- V transpose: qkv[t][2C + h*64 + d] -> vt[(bh*64+d)*SEQ + t] ----------------
__global__ __launch_bounds__(256) void k_vtrans(
    const bf16* __restrict__ qkv, bf16* __restrict__ vt)
{
    __shared__ bf16 tile[32][33];
    int tt = blockIdx.x;                 // t tile (SEQ/32)
    int bh = blockIdx.y;                 // 24
    int dt = blockIdx.z;                 // d tile (2)
    int b = bh / N_HEAD, h = bh % N_HEAD;
    int tc = threadIdx.x & 31, tr = threadIdx.x >> 5;
    #pragma unroll
    for (int i = 0; i < 4; i++) {
        int r = tr + i * 8;              // t offset
        tile[r][tc] = qkv[(size_t)(b * SEQ + tt * 32 + r) * C3 + 2 * N_EMBD + h * 64 + dt * 32 + tc];
    }
    __syncthreads();
    #pragma unroll
    for (int i = 0; i < 4; i++) {
        int r = tr + i * 8;              // d offset
        vt[(size_t)(bh * 64 + dt * 32 + r) * SEQ + tt * 32 + tc] = tile[tc][r];
    }
}

// ---------------- LayerNorm fp32 -> bf16, one wave per row, float4 loads ----------------
__global__ __launch_bounds__(256) void k_layernorm(
    const float* __restrict__ x, const float* __restrict__ g,
    const float* __restrict__ b, bf16* __restrict__ out)
{
    int wave = threadIdx.x >> 6, lane = threadIdx.x & 63;
    int row = blockIdx.x * 4 + wave;
    const float4* xr = (const float4*)(x + (size_t)row * N_EMBD);
    const float4* g4 = (const float4*)g;
    const float4* b4 = (const float4*)b;
    float4 v[3];
    float s = 0.f, sq = 0.f;
    #pragma unroll
    for (int i = 0; i < 3; i++) {
        v[i] = xr[lane + 64 * i];
        s  += v[i].x + v[i].y + v[i].z + v[i].w;
        sq += v[i].x * v[i].x + v[i].y * v[i].y + v[i].z * v[i].z + v[i].w * v[i].w;
    }
    #pragma unroll
    for (int off = 32; off > 0; off >>= 1) {
        s  += __shfl_xor(s, off);
        sq += __shfl_xor(sq, off);
    }
    float mu  = s * (1.f / N_EMBD);
    float var = sq * (1.f / N_EMBD) - mu * mu;
    float rs  = rsqrtf(var + 1e-5f);
    bf16* orow = out + (size_t)row * N_EMBD;
    #pragma unroll
    for (int i = 0; i < 3; i++) {
        float4 gv = g4[lane + 64 * i], bv = b4[lane + 64 * i];
        union { ushort4 u4; bf16 e[4]; } pk;
        pk.e[0] = (bf16)((v[i].x - mu) * rs * gv.x + bv.x);
        pk.e[1] = (bf16)((v[i].y - mu) * rs * gv.y + bv.y);
        pk.e[2] = (bf16)((v[i].z - mu) * rs * gv.z + bv.z);
        pk.e[3] = (bf16)((v[i].w - mu) * rs * gv.w + bv.w);
        *(ushort4*)&orow[(lane + 64 * i) * 4] = pk.u4;
    }
}

// ---------------- GEMM (4-wave, 128xBN): r6-validated core ----------------
template<int BN, int ACT, bool RES, bool OUT_BF16, bool MSWAP, bool DBUF>
__global__ __launch_bounds__(256) void k_gemm(
    const bf16* __restrict__ A, const bf16* __restrict__ Bt,
    const float* __restrict__ bias, const float* __restrict__ res,
    void* __restrict__ outp, int M, int N, int K)
{
    constexpr int WC  = BN / 64;
    constexpr int WR  = 4 / WC;
    constexpr int RPW = 128 / WR;
    constexpr int MI  = RPW / 16;
    constexpr int NB  = DBUF ? 2 : 1;
    __shared__ __align__(16) bf16 As[NB][128 * 64];
    __shared__ __align__(16) bf16 Bs[NB][BN * 64];
    int n0 = (MSWAP ? blockIdx.y : blockIdx.x) * BN;
    int m0 = (MSWAP ? blockIdx.x : blockIdx.y) * 128;
    int t = threadIdx.x;
    int lane = t & 63, wave = t >> 6;
    int wr = wave / WC, wc = wave % WC;
    int quad = lane >> 4, l16 = lane & 15;

    f32x4 acc[MI][4];
    #pragma unroll
    for (int i = 0; i < MI; i++)
        #pragma unroll
        for (int j = 0; j < 4; j++) acc[i][j] = (f32x4){0.f, 0.f, 0.f, 0.f};

    int sr = t >> 3;            // 0..31 (row)
    int sc = t & 7;             // chunk 0..7 (8 bf16 = 16B)
    int gsw = (sc ^ (sr & 7)) * 8;   // swizzled global column offset

    auto stage = [&](int k0, int bi) {
        #pragma unroll
        for (int p = 0; p < 4; p++) {
            int r = sr + p * 32;
            async16(&A[(size_t)(m0 + r) * K + k0 + gsw], &As[bi][r * 64 + sc * 8]);
        }
        #pragma unroll
        for (int p = 0; p < BN / 32; p++) {
            int r = sr + p * 32;
            async16(&Bt[(size_t)(n0 + r) * K + k0 + gsw], &Bs[bi][r * 64 + sc * 8]);
        }
    };
    auto compute = [&](int bi) {
        #pragma unroll
        for (int kh = 0; kh < 2; kh++) {
            bf16x8 af[MI], bfv[4];
            #pragma unroll
            for (int i = 0; i < MI; i++)
                af[i]  = *(bf16x8*)&As[bi][(wr * RPW + i * 16 + l16) * 64 + (((quad + 4 * kh) ^ (l16 & 7)) * 8)];
            #pragma unroll
            for (int j = 0; j < 4; j++)
                bfv[j] = *(bf16x8*)&Bs[bi][(wc * 64 + j * 16 + l16) * 64 + (((quad + 4 * kh) ^ (l16 & 7)) * 8)];
            #pragma unroll
            for (int i = 0; i < MI; i++)
                #pragma unroll
                for (int j = 0; j < 4; j++)
                    acc[i][j] = __builtin_amdgcn_mfma_f32_16x16x32_bf16(af[i], bfv[j], acc[i][j], 0, 0, 0);
        }
    };

    if (DBUF) {
        stage(0, 0);
        int bi = 0;
        for (int k0 = 0; k0 < K; k0 += 64, bi ^= 1) {
            __syncthreads();
            if (k0 + 64 < K) stage(k0 + 64, bi ^ 1);
            compute(bi);
        }
    } else {
        for (int k0 = 0; k0 < K; k0 += 64) {
            __syncthreads();
            stage(k0, 0);
            __syncthreads();
            compute(0);
        }
    }

    float* outf = (float*)outp;
    bf16*  outb = (bf16*)outp;
    #pragma unroll
    for (int i = 0; i < MI; i++) {
        #pragma unroll
        for (int j = 0; j < 4; j++) {
            int col = n0 + wc * 64 + j * 16 + l16;
            float bv = bias[col];
            #pragma unroll
            for (int r = 0; r < 4; r++) {
                int row = m0 + wr * RPW + i * 16 + quad * 4 + r;
                float v = acc[i][j][r] + bv;
                if (ACT == 1) {
                    float z = 0.7978845608f * (v + 0.044715f * v * v * v);
                    v = v / (1.f + __expf(-2.f * z));   // 0.5v(1+tanh z) == v*sigmoid(2z)
                }
                if (RES) v += res[(size_t)row * N + col];
                if (OUT_BF16) outb[(size_t)row * N + col] = (bf16)v;
                else          outf[(size_t)row * N + col] = v;
            }
        }
    }
}

// ---------------- GEMM2 (4-wave, 64x64 tile, dbuf): for N=768 GEMMs ----------------
// grid (M/64, N/64) m-fast: 768 blocks = exactly 3/CU. 2x2 wave grid, 32x32 per wave.
// fp32 out + residual, no activation.
__global__ __launch_bounds__(256) void k_gemm2(
    const bf16* __restrict__ A, const bf16* __restrict__ Bt,
    const float* __restrict__ bias, const float* __restrict__ res,
    float* __restrict__ outp, int M, int N, int K)
{
    __shared__ __align__(16) bf16 As[2][64 * 64];
    __shared__ __align__(16) bf16 Bs[2][64 * 64];
    int m0 = blockIdx.x * 64, n0 = blockIdx.y * 64;
    int t = threadIdx.x;
    int lane = t & 63, w = t >> 6;       // w 0..3
    int wr = w >> 1, wcol = w & 1;       // 2x2 wave grid
    int quad = lane >> 4, l16 = lane & 15;

    f32x4 acc[2][2];
    #pragma unroll
    for (int i = 0; i < 2; i++)
        #pragma unroll
        for (int j = 0; j < 2; j++) acc[i][j] = (f32x4){0.f, 0.f, 0.f, 0.f};

    int sr = t >> 3;            // 0..31 (row)
    int sc = t & 7;             // chunk 0..7
    int gsw = (sc ^ (sr & 7)) * 8;   // (sr+32)&7 == sr&7

    auto stage = [&](int k0, int bi) {
        #pragma unroll
        for (int p = 0; p < 2; p++) {
            int r = sr + p * 32;
            async16(&A[(size_t)(m0 + r) * K + k0 + gsw], &As[bi][r * 64 + sc * 8]);
            async16(&Bt[(size_t)(n0 + r) * K + k0 + gsw], &Bs[bi][r * 64 + sc * 8]);
        }
    };
    auto compute = [&](int bi) {
        #pragma unroll
        for (int kh = 0; kh < 2; kh++) {
            int rsw = ((quad + 4 * kh) ^ (l16 & 7)) * 8;
            bf16x8 af[2], bfv[2];
            #pragma unroll
            for (int i = 0; i < 2; i++)
                af[i]  = *(bf16x8*)&As[bi][(wr * 32 + i * 16 + l16) * 64 + rsw];
            #pragma unroll
            for (int j = 0; j < 2; j++)
                bfv[j] = *(bf16x8*)&Bs[bi][(wcol * 32 + j * 16 + l16) * 64 + rsw];
            #pragma unroll
            for (int i = 0; i < 2; i++)
                #pragma unroll
                for (int j = 0; j < 2; j++)
                    acc[i][j] = __builtin_amdgcn_mfma_f32_16x16x32_bf16(af[i], bfv[j], acc[i][j], 0, 0, 0);
        }
    };

    stage(0, 0);
    int bi = 0;
    for (int k0 = 0; k0 < K; k0 += 64, bi ^= 1) {
        __syncthreads();
        if (k0 + 64 < K) stage(k0 + 64, bi ^ 1);
        compute(bi);
    }

    #pragma unroll
    for (int i = 0; i < 2; i++) {
        #pragma unroll
        for (int j = 0; j < 2; j++) {
            int col = n0 + wcol * 32 + j * 16 + l16;
            float bv = bias[col];
            #pragma unroll
            for (int r = 0; r < 4; r++) {
                int row = m0 + wr * 32 + i * 16 + quad * 4 + r;
                outp[(size_t)row * N + col] = acc[i][j][r] + bv + res[(size_t)row * N + col];
            }
        }
    }
}

// ---------------- Flash attention v11: split-K over key range -> 1920 near-equal blocks ----------------
// r4 post-mortem: balanced-sum triples give each CU 3 blocks of unequal length (1,17,31);
// the CU spends most of the kernel at 1-2 resident blocks -> measured 17% occupancy.
// v11: each q-tile's key range is split into ceil((qt+1)/8) pieces of <=8 key-tiles.
// 1920 blocks (avg 6.6 tiles), heavy-first; with 40960B LDS (4 blocks/CU capacity from r4)
// CUs dynamically refill and stay at ~16 waves. Blocks write unnormalized partial (o,l)
// in f32 (plain exp, no running max -> partials sum exactly); k_combine normalizes.
// Also: Q pre-scaled by log2(e)/8 so softmax uses exp2f (saves 16 v_mul/tile).
__global__ __launch_bounds__(256) void k_flash(
    const bf16* __restrict__ qkv, const bf16* __restrict__ vt,
    float* __restrict__ opart, float* __restrict__ lpart)
{
    __shared__ __align__(16) bf16 Ks[2][64 * 64];      // [buf][key][d^swz]
    __shared__ __align__(16) bf16 VTl[2][64 * 64];     // [buf][d][key^swz]
    __shared__ __align__(16) bf16 Ps[4][16 * 64];      // per-wave [q][key^swz]

    // bid -> (qt, piece, bh), qt descending (heavy pieces dispatched first)
    int bid = blockIdx.x;
    int qt = 0, piece = 0, bh = 0;
    {
        int acc = 0;
        #pragma unroll 1
        for (int q = 31; q >= 0; q--) {
            int nsq = (q + 8) >> 3;          // ceil((q+1)/8)
            int cnt = 24 * nsq;
            if (bid < acc + cnt) { qt = q; int r = bid - acc; piece = r / 24; bh = r % 24; break; }
            acc += cnt;
        }
    }
    int ns    = (qt + 8) >> 3;
    int total = qt + 1;
    int base  = total / ns, rem = total % ns;
    int t0 = piece * base + (piece < rem ? piece : rem);
    int t1 = t0 + base + (piece < rem ? 1 : 0);

    int b = bh / N_HEAD, h = bh % N_HEAD;
    int t = threadIdx.x, lane = t & 63, wave = t >> 6;
    int quad = lane >> 4, l16 = lane & 15;
    int qbase = qt * 64 + wave * 16;

    // Q fragments, pre-scaled by log2(e)/8 (softmax becomes exp2)
    bf16x8 qa[2];
    {
        const float qsc = 0.125f * 1.44269504089f;
        const bf16* qrow = qkv + (size_t)(b * SEQ + qbase + l16) * C3 + h * 64;
        #pragma unroll
        for (int kh = 0; kh < 2; kh++) {
            union { uint4 u4; bf16 e8[8]; bf16x8 vv; } uq;
            uq.u4 = *(const uint4*)&qrow[quad * 8 + kh * 32];
            #pragma unroll
            for (int j = 0; j < 8; j++) uq.e8[j] = (bf16)((float)uq.e8[j] * qsc);
            qa[kh] = uq.vv;
        }
    }
    float l_part[4] = {0.f, 0.f, 0.f, 0.f};
    f32x4 o[4];
    #pragma unroll
    for (int j = 0; j < 4; j++) o[j] = (f32x4){0.f, 0.f, 0.f, 0.f};

    int sr = t >> 3;                 // 0..31
    int sc = t & 7;                  // 16B chunk
    int gsw = (sc ^ (sr & 7)) * 8;   // swizzled column offset

    const bf16* kg = qkv + (size_t)b * SEQ * C3 + N_EMBD + h * 64;
    const bf16* vg = vt + (size_t)bh * 64 * SEQ;

    auto stage = [&](int tile, int bufi) {
        int k0 = tile * 64;
        #pragma unroll
        for (int p = 0; p < 2; p++) {
            int rr = sr + 32 * p;
            async16(&kg[(size_t)(k0 + rr) * C3 + gsw],  &Ks[bufi][rr * 64 + sc * 8]);
            async16(&vg[(size_t)rr * SEQ + k0 + gsw], &VTl[bufi][rr * 64 + sc * 8]);
        }
    };

    stage(t0, 0);

    for (int tt = t0; tt < t1; tt++) {
        int bufi = (tt - t0) & 1;
        int k0 = tt * 64;
        __syncthreads();                       // drains buf's loads (issued a full tile ago)
        if (tt + 1 < t1) stage(tt + 1, bufi ^ 1);

        // S = Q K^T : 4 key-tiles of 16
        f32x4 s[4];
        __builtin_amdgcn_s_setprio(1);
        #pragma unroll
        for (int nt = 0; nt < 4; nt++) {
            bf16x8 b0 = *(bf16x8*)&Ks[bufi][(nt * 16 + l16) * 64 + (((quad    ) ^ (l16 & 7)) * 8)];
            bf16x8 b1 = *(bf16x8*)&Ks[bufi][(nt * 16 + l16) * 64 + (((quad + 4) ^ (l16 & 7)) * 8)];
            f32x4 z = (f32x4){0.f, 0.f, 0.f, 0.f};
            z = __builtin_amdgcn_mfma_f32_16x16x32_bf16(qa[0], b0, z, 0, 0, 0);
            z = __builtin_amdgcn_mfma_f32_16x16x32_bf16(qa[1], b1, z, 0, 0, 0);
            s[nt] = z;
        }
        __builtin_amdgcn_s_setprio(0);
        // p = exp2(s); causal zeroing only on the diagonal tile (last piece only)
        bool diag = (tt == qt);
        float p[4][4];
        #pragma unroll
        for (int nt = 0; nt < 4; nt++) {
            int key = k0 + nt * 16 + l16;
            #pragma unroll
            for (int r = 0; r < 4; r++) {
                float pv = exp2f(s[nt][r]);
                if (diag && key > qbase + quad * 4 + r) pv = 0.f;
                p[nt][r] = pv;
                l_part[r] += pv;
            }
        }
        // P: C-layout -> per-wave LDS -> A-layout (wave-local, no block barrier)
        // swizzled layout: elem (q,key) at q*64 + (key ^ ((q&7)<<3)); chunk-aligned
        #pragma unroll
        for (int nt = 0; nt < 4; nt++)
            #pragma unroll
            for (int r = 0; r < 4; r++) {
                int q = quad * 4 + r;
                Ps[wave][q * 64 + ((nt * 16 + l16) ^ ((q & 7) << 3))] = (bf16)p[nt][r];
            }
        bf16x8 pa[2];
        #pragma unroll
        for (int kt = 0; kt < 2; kt++)
            pa[kt] = *(bf16x8*)&Ps[wave][l16 * 64 + ((kt * 32 + quad * 8) ^ ((l16 & 7) << 3))];
        // O += P V
        __builtin_amdgcn_s_setprio(1);
        #pragma unroll
        for (int jt = 0; jt < 4; jt++) {
            int d = jt * 16 + l16;
            #pragma unroll
            for (int kt = 0; kt < 2; kt++) {
                bf16x8 vb = *(bf16x8*)&VTl[bufi][d * 64 + (((quad + 4 * kt) ^ (l16 & 7)) * 8)];
                o[jt] = __builtin_amdgcn_mfma_f32_16x16x32_bf16(pa[kt], vb, o[jt], 0, 0, 0);
            }
        }
        __builtin_amdgcn_s_setprio(0);
    }
    // epilogue: reduce row sums across the 16-lane key groups, store unnormalized partials
    #pragma unroll
    for (int r = 0; r < 4; r++) {
        #pragma unroll
        for (int off = 8; off > 0; off >>= 1) l_part[r] += __shfl_xor(l_part[r], off);
    }
    #pragma unroll
    for (int jt = 0; jt < 4; jt++)
        #pragma unroll
        for (int r = 0; r < 4; r++) {
            size_t row = (size_t)piece * ROWS + b * SEQ + qbase + quad * 4 + r;
            opart[row * N_EMBD + h * 64 + jt * 16 + l16] = o[jt][r];
        }
    if (l16 == 0) {
        #pragma unroll
        for (int r = 0; r < 4; r++) {
            size_t row = (size_t)piece * ROWS + b * SEQ + qbase + quad * 4 + r;
            lpart[row * N_HEAD + h] = l_part[r];
        }
    }
}

// ---------------- combine split-K partials: y = (sum_p o_p) / (sum_p l_p), bf16 ----------------
__global__ __launch_bounds__(256) void k_combine(
    const float* __restrict__ opart, const float* __restrict__ lpart,
    bf16* __restrict__ y)
{
    int row = blockIdx.x;                 // 0..ROWS-1
    int q = row & (SEQ - 1);
    int ns = ((q >> 6) + 8) >> 3;         // pieces for this q's tile
    int t = threadIdx.x;
    #pragma unroll
    for (int i = 0; i < 3; i++) {
        int col = t + 256 * i;
        float ov = 0.f, lv = 0.f;
        for (int p = 0; p < ns; p++) {
            size_t prow = (size_t)p * ROWS + row;
            ov += opart[prow * N_EMBD + col];
            lv += lpart[prow * N_HEAD + (col >> 6)];
        }
        y[(size_t)row * N_EMBD + col] = (bf16)(ov / lv);
    }
}

// ---------------- launcher ----------------
extern "C" void kernel_launch(void* const* d_in, const int* in_sizes, int n_in,
                              void* d_out, int out_size, void* d_ws, size_t ws_size,
                              hipStream_t stream) {
    const float* x           = (const float*)d_in[0];
    const float* ln1_g       = (const float*)d_in[1];
    const float* ln1_b       = (const float*)d_in[2];
    const float* w_attn      = (const float*)d_in[3];
    const float* b_attn      = (const float*)d_in[4];
    const float* w_attn_proj = (const float*)d_in[5];
    const float* b_attn_proj = (const float*)d_in[6];
    const float* ln2_g       = (const float*)d_in[7];
    const float* ln2_b       = (const float*)d_in[8];
    const float* w_fc        = (const float*)d_in[9];
    const float* b_fc        = (const float*)d_in[10];
    const float* w_mlp_proj  = (const float*)d_in[11];
    const float* b_mlp_proj  = (const float*)d_in[12];

    char* ws = (char*)d_ws;
    size_t off = 0;
    auto alloc = [&](size_t n) -> void* {
        off = (off + 255) & ~(size_t)255;
        void* p = ws + off;
        off += n;
        return p;
    };
    bf16* wqkvT  = (bf16*)alloc((size_t)C3 * N_EMBD * 2);
    bf16* wprojT = (bf16*)alloc((size_t)N_EMBD * N_EMBD * 2);
    bf16* wfcT   = (bf16*)alloc((size_t)4 * N_EMBD * N_EMBD * 2);
    bf16* wmlpT  = (bf16*)alloc((size_t)N_EMBD * 4 * N_EMBD * 2);
    bf16* hbuf   = (bf16*)alloc((size_t)ROWS * N_EMBD * 2);
    float* x2    = (float*)alloc((size_t)ROWS * N_EMBD * 4);
    bf16* yb     = (bf16*)alloc((size_t)ROWS * N_EMBD * 2);
    bf16* vtb    = (bf16*)alloc((size_t)BATCH * N_HEAD * 64 * SEQ * 2);
    bf16* big    = (bf16*)alloc((size_t)ROWS * 4 * N_EMBD * 2);
    bf16* qkvb   = big;        // [ROWS, 2304]
    bf16* actb   = big;        // [ROWS, 3072]
    float* opartb = (float*)alloc((size_t)4 * ROWS * N_EMBD * 4);   // split-K partial O
    float* lpartb = (float*)alloc((size_t)4 * ROWS * N_HEAD * 4);   // split-K partial l

    k_transpose_all<<<6912, 256, 0, stream>>>(w_attn, wqkvT, w_attn_proj, wprojT,
                                              w_fc, wfcT, w_mlp_proj, wmlpT);

    k_layernorm<<<ROWS / 4, 256, 0, stream>>>(x, ln1_g, ln1_b, hbuf);
    // qkv: m-fast grid for A locality
    k_gemm<128, 0, false, true,  true,  false><<<dim3(ROWS / 128, C3 / 128), 256, 0, stream>>>(
        hbuf, wqkvT,  b_attn,      nullptr, qkvb, ROWS, C3,     N_EMBD);
    k_vtrans<<<dim3(SEQ / 32, BATCH * N_HEAD, 2), 256, 0, stream>>>(qkvb, vtb);
    k_flash<<<1920, 256, 0, stream>>>(qkvb, vtb, opartb, lpartb);
    k_combine<<<ROWS, 256, 0, stream>>>(opartb, lpartb, yb);
    // proj: 64x64 4-wave blocks, 3 blocks/CU
    k_gemm2<<<dim3(ROWS / 64, N_EMBD / 64), 256, 0, stream>>>(
        yb,   wprojT, b_attn_proj, x,       x2,   ROWS, N_EMBD, N_EMBD);
    k_layernorm<<<ROWS / 4, 256, 0, stream>>>(x2, ln2_g, ln2_b, hbuf);
    // fc: m-fast grid, single-buffer (BN=128)
    k_gemm<128, 1, false, true,  true,  false><<<dim3(ROWS / 128, 3072 / 128), 256, 0, stream>>>(
        hbuf, wfcT,   b_fc,        nullptr, actb, ROWS, 3072,   N_EMBD);
    // mlp: 64x64 4-wave blocks, 3 blocks/CU
    k_gemm2<<<dim3(ROWS / 64, N_EMBD / 64), 256, 0, stream>>>(
        actb, wmlpT,  b_mlp_proj,  x2, (float*)d_out, ROWS, N_EMBD, 3072);
}

// Round 6
// 260.415 us; speedup vs baseline: 1.0364x; 1.0364x over previous
//
#include <hip/hip_runtime.h>
#include <hip/hip_bf16.h>
#include <math.h>

#define N_EMBD 768
#define N_HEAD 12
#define BATCH  2
#define SEQ    2048
#define ROWS   (BATCH*SEQ)   // 4096
#define C3     (3*N_EMBD)    // 2304

typedef __bf16 bf16;
typedef __attribute__((ext_vector_type(8))) __bf16 bf16x8;
typedef __attribute__((ext_vector_type(4))) float f32x4;

// async global->LDS, 16B per lane. LDS dest must be wave-uniform base + 16*lane.
__device__ __forceinline__ void async16(const bf16* g, bf16* l) {
    __builtin_amdgcn_global_load_lds(
        (const __attribute__((address_space(1))) uint32_t*)g,
        (__attribute__((address_space(3))) uint32_t*)l, 16, 0, 0);
}

// ---------------- merged transpose+cast for all 4 weights: in[K,N] -> out[N,K] ----------------
__global__ __launch_bounds__(256) void k_transpose_all(
    const float* __restrict__ w0, bf16* __restrict__ o0,   // attn K=768  N=2304 (1728 tiles)
    const float* __restrict__ w1, bf16* __restrict__ o1,   // proj K=768  N=768  (576)
    const float* __restrict__ w2, bf16* __restrict__ o2,   // fc   K=768  N=3072 (2304)
    const float* __restrict__ w3, bf16* __restrict__ o3)   // mlp  K=3072 N=768  (2304)
{
    __shared__ bf16 tile[32][33];
    int bid = blockIdx.x;
    const float* in; bf16* out; int K, N, local;
    if      (bid < 1728) { in = w0; out = o0; K = 768;  N = 2304; local = bid; }
    else if (bid < 2304) { in = w1; out = o1; K = 768;  N = 768;  local = bid - 1728; }
    else if (bid < 4608) { in = w2; out = o2; K = 768;  N = 3072; local = bid - 2304; }
    else                 { in = w3; out = o3; K = 3072; N = 768;  local = bid - 4608; }
    int nt = N / 32;
    int n0 = (local % nt) * 32, k0 = (local / nt) * 32;
    int tc = threadIdx.x & 31, tr = threadIdx.x >> 5;
    #pragma unroll
    for (int i = 0; i < 4; i++) {
        int r = tr + i * 8;
        tile[r][tc] = (bf16)in[(size_t)(k0 + r) * N + n0 + tc];
    }
    __syncthreads();
    #pragma unroll
    for (int i = 0; i < 4; i++) {
        int r = tr + i * 8;
        out[(size_t)(n0 + r) * K + k0 + tc] = tile[tc][r];
    }
}

// ---------------- V transpose: qkv[t][2C + h*64 + d] -> vt[(bh*64+d)*SEQ + t] ----------------
__global__ __launch_bounds__(256) void k_vtrans(
    const bf16* __restrict__ qkv, bf16* __restrict__ vt)
{
    __shared__ bf16 tile[32][33];
    int tt = blockIdx.x;                 // t tile (SEQ/32)
    int bh = blockIdx.y;                 // 24
    int dt = blockIdx.z;                 // d tile (2)
    int b = bh / N_HEAD, h = bh % N_HEAD;
    int tc = threadIdx.x & 31, tr = threadIdx.x >> 5;
    #pragma unroll
    for (int i = 0; i < 4; i++) {
        int r = tr + i * 8;              // t offset
        tile[r][tc] = qkv[(size_t)(b * SEQ + tt * 32 + r) * C3 + 2 * N_EMBD + h * 64 + dt * 32 + tc];
    }
    __syncthreads();
    #pragma unroll
    for (int i = 0; i < 4; i++) {
        int r = tr + i * 8;              // d offset
        vt[(size_t)(bh * 64 + dt * 32 + r) * SEQ + tt * 32 + tc] = tile[tc][r];
    }
}

// ---------------- LayerNorm fp32 -> bf16, one wave per row, float4 loads ----------------
__global__ __launch_bounds__(256) void k_layernorm(
    const float* __restrict__ x, const float* __restrict__ g,
    const float* __restrict__ b, bf16* __restrict__ out)
{
    int wave = threadIdx.x >> 6, lane = threadIdx.x & 63;
    int row = blockIdx.x * 4 + wave;
    const float4* xr = (const float4*)(x + (size_t)row * N_EMBD);
    const float4* g4 = (const float4*)g;
    const float4* b4 = (const float4*)b;
    float4 v[3];
    float s = 0.f, sq = 0.f;
    #pragma unroll
    for (int i = 0; i < 3; i++) {
        v[i] = xr[lane + 64 * i];
        s  += v[i].x + v[i].y + v[i].z + v[i].w;
        sq += v[i].x * v[i].x + v[i].y * v[i].y + v[i].z * v[i].z + v[i].w * v[i].w;
    }
    #pragma unroll
    for (int off = 32; off > 0; off >>= 1) {
        s  += __shfl_xor(s, off);
        sq += __shfl_xor(sq, off);
    }
    float mu  = s * (1.f / N_EMBD);
    float var = sq * (1.f / N_EMBD) - mu * mu;
    float rs  = rsqrtf(var + 1e-5f);
    bf16* orow = out + (size_t)row * N_EMBD;
    #pragma unroll
    for (int i = 0; i < 3; i++) {
        float4 gv = g4[lane + 64 * i], bv = b4[lane + 64 * i];
        union { ushort4 u4; bf16 e[4]; } pk;
        pk.e[0] = (bf16)((v[i].x - mu) * rs * gv.x + bv.x);
        pk.e[1] = (bf16)((v[i].y - mu) * rs * gv.y + bv.y);
        pk.e[2] = (bf16)((v[i].z - mu) * rs * gv.z + bv.z);
        pk.e[3] = (bf16)((v[i].w - mu) * rs * gv.w + bv.w);
        *(ushort4*)&orow[(lane + 64 * i) * 4] = pk.u4;
    }
}

// ---------------- GEMM (4-wave, 128xBN, BK templated): r6-validated core + BK=32 dbuf path ----------------
// BK=64 path identical to prior rounds. BK=32+DBUF: LDS 32KB (same 5-blk/CU capacity as
// single-buffer BK=64) but ONE barrier per K-step with stage(k+1) overlapping compute(k).
// BK=32 swizzle: chunk ^= (row&3)^((row>>2)&3) (64B rows; plain row&3 left rows 4 apart
// on the same banks -> 4-way; the extra term spreads them, leaving free 2-way).
template<int BN, int BK, int ACT, bool RES, bool OUT_BF16, bool MSWAP, bool DBUF>
__global__ __launch_bounds__(256) void k_gemm(
    const bf16* __restrict__ A, const bf16* __restrict__ Bt,
    const float* __restrict__ bias, const float* __restrict__ res,
    void* __restrict__ outp, int M, int N, int K)
{
    constexpr int WC  = BN / 64;
    constexpr int WR  = 4 / WC;
    constexpr int RPW = 128 / WR;
    constexpr int MI  = RPW / 16;
    constexpr int NB  = DBUF ? 2 : 1;
    constexpr int KH  = BK / 32;          // 16x16x32 passes per K-step
    constexpr int CPR = BK / 8;           // 16B chunks per row
    constexpr int RSTEP = 256 / CPR;      // rows staged per pass
    __shared__ __align__(16) bf16 As[NB][128 * BK];
    __shared__ __align__(16) bf16 Bs[NB][BN * BK];
    int n0 = (MSWAP ? blockIdx.y : blockIdx.x) * BN;
    int m0 = (MSWAP ? blockIdx.x : blockIdx.y) * 128;
    int t = threadIdx.x;
    int lane = t & 63, wave = t >> 6;
    int wr = wave / WC, wc = wave % WC;
    int quad = lane >> 4, l16 = lane & 15;

    f32x4 acc[MI][4];
    #pragma unroll
    for (int i = 0; i < MI; i++)
        #pragma unroll
        for (int j = 0; j < 4; j++) acc[i][j] = (f32x4){0.f, 0.f, 0.f, 0.f};

    int sr = t / CPR;           // staging row
    int sc = t % CPR;           // staging chunk
    int fsw = (BK == 64) ? (sr & 7) : ((sr & 3) ^ ((sr >> 2) & 3));
    int gsw = (sc ^ fsw) * 8;   // swizzled global column offset
    // read-side row swizzle term (row base is a multiple of 16 everywhere)
    int lsw = (BK == 64) ? (l16 & 7) : ((l16 & 3) ^ ((l16 >> 2) & 3));

    auto stage = [&](int k0, int bi) {
        #pragma unroll
        for (int p = 0; p < 128 / RSTEP; p++) {
            int r = sr + p * RSTEP;
            async16(&A[(size_t)(m0 + r) * K + k0 + gsw], &As[bi][r * BK + sc * 8]);
        }
        #pragma unroll
        for (int p = 0; p < BN / RSTEP; p++) {
            int r = sr + p * RSTEP;
            async16(&Bt[(size_t)(n0 + r) * K + k0 + gsw], &Bs[bi][r * BK + sc * 8]);
        }
    };
    auto compute = [&](int bi) {
        #pragma unroll
        for (int kh = 0; kh < KH; kh++) {
            int qk = quad + 4 * kh;
            bf16x8 af[MI], bfv[4];
            #pragma unroll
            for (int i = 0; i < MI; i++)
                af[i]  = *(bf16x8*)&As[bi][(wr * RPW + i * 16 + l16) * BK + ((qk ^ lsw) * 8)];
            #pragma unroll
            for (int j = 0; j < 4; j++)
                bfv[j] = *(bf16x8*)&Bs[bi][(wc * 64 + j * 16 + l16) * BK + ((qk ^ lsw) * 8)];
            #pragma unroll
            for (int i = 0; i < MI; i++)
                #pragma unroll
                for (int j = 0; j < 4; j++)
                    acc[i][j] = __builtin_amdgcn_mfma_f32_16x16x32_bf16(af[i], bfv[j], acc[i][j], 0, 0, 0);
        }
    };

    if (DBUF) {
        stage(0, 0);
        int bi = 0;
        for (int k0 = 0; k0 < K; k0 += BK, bi ^= 1) {
            __syncthreads();
            if (k0 + BK < K) stage(k0 + BK, bi ^ 1);
            compute(bi);
        }
    } else {
        for (int k0 = 0; k0 < K; k0 += BK) {
            __syncthreads();
            stage(k0, 0);
            __syncthreads();
            compute(0);
        }
    }

    float* outf = (float*)outp;
    bf16*  outb = (bf16*)outp;
    #pragma unroll
    for (int i = 0; i < MI; i++) {
        #pragma unroll
        for (int j = 0; j < 4; j++) {
            int col = n0 + wc * 64 + j * 16 + l16;
            float bv = bias[col];
            #pragma unroll
            for (int r = 0; r < 4; r++) {
                int row = m0 + wr * RPW + i * 16 + quad * 4 + r;
                float v = acc[i][j][r] + bv;
                if (ACT == 1) {
                    float z = 0.7978845608f * (v + 0.044715f * v * v * v);
                    v = v / (1.f + __expf(-2.f * z));   // 0.5v(1+tanh z) == v*sigmoid(2z)
                }
                if (RES) v += res[(size_t)row * N + col];
                if (OUT_BF16) outb[(size_t)row * N + col] = (bf16)v;
                else          outf[(size_t)row * N + col] = v;
            }
        }
    }
}

// ---------------- GEMM2 (4-wave, 64x64 tile, dbuf): for N=768 GEMMs ----------------
// grid (M/64, N/64) m-fast: 768 blocks = exactly 3/CU. 2x2 wave grid, 32x32 per wave.
// fp32 out + residual, no activation.
__global__ __launch_bounds__(256) void k_gemm2(
    const bf16* __restrict__ A, const bf16* __restrict__ Bt,
    const float* __restrict__ bias, const float* __restrict__ res,
    float* __restrict__ outp, int M, int N, int K)
{
    __shared__ __align__(16) bf16 As[2][64 * 64];
    __shared__ __align__(16) bf16 Bs[2][64 * 64];
    int m0 = blockIdx.x * 64, n0 = blockIdx.y * 64;
    int t = threadIdx.x;
    int lane = t & 63, w = t >> 6;       // w 0..3
    int wr = w >> 1, wcol = w & 1;       // 2x2 wave grid
    int quad = lane >> 4, l16 = lane & 15;

    f32x4 acc[2][2];
    #pragma unroll
    for (int i = 0; i < 2; i++)
        #pragma unroll
        for (int j = 0; j < 2; j++) acc[i][j] = (f32x4){0.f, 0.f, 0.f, 0.f};

    int sr = t >> 3;            // 0..31 (row)
    int sc = t & 7;             // chunk 0..7
    int gsw = (sc ^ (sr & 7)) * 8;   // (sr+32)&7 == sr&7

    auto stage = [&](int k0, int bi) {
        #pragma unroll
        for (int p = 0; p < 2; p++) {
            int r = sr + p * 32;
            async16(&A[(size_t)(m0 + r) * K + k0 + gsw], &As[bi][r * 64 + sc * 8]);
            async16(&Bt[(size_t)(n0 + r) * K + k0 + gsw], &Bs[bi][r * 64 + sc * 8]);
        }
    };
    auto compute = [&](int bi) {
        #pragma unroll
        for (int kh = 0; kh < 2; kh++) {
            int rsw = ((quad + 4 * kh) ^ (l16 & 7)) * 8;
            bf16x8 af[2], bfv[2];
            #pragma unroll
            for (int i = 0; i < 2; i++)
                af[i]  = *(bf16x8*)&As[bi][(wr * 32 + i * 16 + l16) * 64 + rsw];
            #pragma unroll
            for (int j = 0; j < 2; j++)
                bfv[j] = *(bf16x8*)&Bs[bi][(wcol * 32 + j * 16 + l16) * 64 + rsw];
            #pragma unroll
            for (int i = 0; i < 2; i++)
                #pragma unroll
                for (int j = 0; j < 2; j++)
                    acc[i][j] = __builtin_amdgcn_mfma_f32_16x16x32_bf16(af[i], bfv[j], acc[i][j], 0, 0, 0);
        }
    };

    stage(0, 0);
    int bi = 0;
    for (int k0 = 0; k0 < K; k0 += 64, bi ^= 1) {
        __syncthreads();
        if (k0 + 64 < K) stage(k0 + 64, bi ^ 1);
        compute(bi);
    }

    #pragma unroll
    for (int i = 0; i < 2; i++) {
        #pragma unroll
        for (int j = 0; j < 2; j++) {
            int col = n0 + wcol * 32 + j * 16 + l16;
            float bv = bias[col];
            #pragma unroll
            for (int r = 0; r < 4; r++) {
                int row = m0 + wr * 32 + i * 16 + quad * 4 + r;
                outp[(size_t)row * N + col] = acc[i][j][r] + bv + res[(size_t)row * N + col];
            }
        }
    }
}

// ---------------- Flash attention v10 (r4-best): QBLK=64, staged dbuf K/V, Ps XOR-swizzle ----------------
// r5 post-mortem: split-K raised occupancy 17->29% with dur unchanged -> flash is NOT
// wave-supply-limited; per-tile serial chain is the floor. Keep the best measured variant
// (43.7us, 0 bank conflicts, LDS 40960).
__global__ __launch_bounds__(256) void k_flash(
    const bf16* __restrict__ qkv, const bf16* __restrict__ vt, bf16* __restrict__ y)
{
    __shared__ __align__(16) bf16 Ks[2][64 * 64];      // [buf][key][d^swz]
    __shared__ __align__(16) bf16 VTl[2][64 * 64];     // [buf][d][key^swz]
    __shared__ __align__(16) bf16 Ps[4][16 * 64];      // per-wave [q][key^swz]
    int bid = blockIdx.x;
    int hi = bid >> 8;                   // 0..2
    int lo = bid & 255;
    int g  = lo >> 3;                    // 0..31
    int e  = lo & 7;                     // 0..7
    int bh = hi * 8 + e;                 // 0..23
    int qt;
    if      (hi == 0) qt = g;
    else if (hi == 1) qt = (g + 16) & 31;
    else              qt = (g < 16) ? (30 - 2 * g) : (63 - 2 * g);
    int b = bh / N_HEAD, h = bh % N_HEAD;
    int t = threadIdx.x, lane = t & 63, wave = t >> 6;
    int quad = lane >> 4, l16 = lane & 15;
    int qbase = qt * 64 + wave * 16;

    // Q fragments, pre-scaled by 1/8
    bf16x8 qa[2];
    {
        const bf16* qrow = qkv + (size_t)(b * SEQ + qbase + l16) * C3 + h * 64;
        #pragma unroll
        for (int kh = 0; kh < 2; kh++) {
            union { uint4 u4; bf16 e8[8]; bf16x8 vv; } uq;
            uq.u4 = *(const uint4*)&qrow[quad * 8 + kh * 32];
            #pragma unroll
            for (int j = 0; j < 8; j++) uq.e8[j] = (bf16)((float)uq.e8[j] * 0.125f);
            qa[kh] = uq.vv;
        }
    }
    float l_part[4] = {0.f, 0.f, 0.f, 0.f};
    f32x4 o[4];
    #pragma unroll
    for (int j = 0; j < 4; j++) o[j] = (f32x4){0.f, 0.f, 0.f, 0.f};

    int sr = t >> 3;                 // 0..31
    int sc = t & 7;                  // 16B chunk
    int gsw = (sc ^ (sr & 7)) * 8;   // swizzled column offset

    const bf16* kg = qkv + (size_t)b * SEQ * C3 + N_EMBD + h * 64;
    const bf16* vg = vt + (size_t)bh * 64 * SEQ;

    auto stage = [&](int tile, int bufi) {
        int k0 = tile * 64;
        #pragma unroll
        for (int p = 0; p < 2; p++) {
            int rr = sr + 32 * p;
            async16(&kg[(size_t)(k0 + rr) * C3 + gsw],  &Ks[bufi][rr * 64 + sc * 8]);
            async16(&vg[(size_t)rr * SEQ + k0 + gsw], &VTl[bufi][rr * 64 + sc * 8]);
        }
    };

    int ntiles = qt + 1;
    stage(0, 0);

    for (int tt = 0; tt < ntiles; tt++) {
        int bufi = tt & 1;
        int k0 = tt * 64;
        __syncthreads();                       // drains buf's loads (issued a full tile ago)
        if (tt + 1 < ntiles) stage(tt + 1, bufi ^ 1);

        // S = Q K^T : 4 key-tiles of 16
        f32x4 s[4];
        __builtin_amdgcn_s_setprio(1);
        #pragma unroll
        for (int nt = 0; nt < 4; nt++) {
            bf16x8 b0 = *(bf16x8*)&Ks[bufi][(nt * 16 + l16) * 64 + (((quad    ) ^ (l16 & 7)) * 8)];
            bf16x8 b1 = *(bf16x8*)&Ks[bufi][(nt * 16 + l16) * 64 + (((quad + 4) ^ (l16 & 7)) * 8)];
            f32x4 z = (f32x4){0.f, 0.f, 0.f, 0.f};
            z = __builtin_amdgcn_mfma_f32_16x16x32_bf16(qa[0], b0, z, 0, 0, 0);
            z = __builtin_amdgcn_mfma_f32_16x16x32_bf16(qa[1], b1, z, 0, 0, 0);
            s[nt] = z;
        }
        __builtin_amdgcn_s_setprio(0);
        // p = exp(s); causal zeroing only on the diagonal tile
        bool diag = (tt == qt);
        float p[4][4];
        #pragma unroll
        for (int nt = 0; nt < 4; nt++) {
            int key = k0 + nt * 16 + l16;
            #pragma unroll
            for (int r = 0; r < 4; r++) {
                float pv = __expf(s[nt][r]);
                if (diag && key > qbase + quad * 4 + r) pv = 0.f;
                p[nt][r] = pv;
                l_part[r] += pv;
            }
        }
        // P: C-layout -> per-wave LDS -> A-layout (wave-local, no block barrier)
        // swizzled layout: elem (q,key) at q*64 + (key ^ ((q&7)<<3)); chunk-aligned
        #pragma unroll
        for (int nt = 0; nt < 4; nt++)
            #pragma unroll
            for (int r = 0; r < 4; r++) {
                int q = quad * 4 + r;
                Ps[wave][q * 64 + ((nt * 16 + l16) ^ ((q & 7) << 3))] = (bf16)p[nt][r];
            }
        bf16x8 pa[2];
        #pragma unroll
        for (int kt = 0; kt < 2; kt++)
            pa[kt] = *(bf16x8*)&Ps[wave][l16 * 64 + ((kt * 32 + quad * 8) ^ ((l16 & 7) << 3))];
        // O += P V
        __builtin_amdgcn_s_setprio(1);
        #pragma unroll
        for (int jt = 0; jt < 4; jt++) {
            int d = jt * 16 + l16;
            #pragma unroll
            for (int kt = 0; kt < 2; kt++) {
                bf16x8 vb = *(bf16x8*)&VTl[bufi][d * 64 + (((quad + 4 * kt) ^ (l16 & 7)) * 8)];
                o[jt] = __builtin_amdgcn_mfma_f32_16x16x32_bf16(pa[kt], vb, o[jt], 0, 0, 0);
            }
        }
        __builtin_amdgcn_s_setprio(0);
    }
    // epilogue: reduce row sums across the 16-lane key groups, divide, store
    #pragma unroll
    for (int r = 0; r < 4; r++) {
        #pragma unroll
        for (int off = 8; off > 0; off >>= 1) l_part[r] += __shfl_xor(l_part[r], off);
    }
    #pragma unroll
    for (int jt = 0; jt < 4; jt++)
        #pragma unroll
        for (int r = 0; r < 4; r++) {
            int q = qbase + quad * 4 + r;
            y[(size_t)(b * SEQ + q) * N_EMBD + h * 64 + jt * 16 + l16] =
                (bf16)(o[jt][r] / l_part[r]);
        }
}

// ---------------- launcher ----------------
extern "C" void kernel_launch(void* const* d_in, const int* in_sizes, int n_in,
                              void* d_out, int out_size, void* d_ws, size_t ws_size,
                              hipStream_t stream) {
    const float* x           = (const float*)d_in[0];
    const float* ln1_g       = (const float*)d_in[1];
    const float* ln1_b       = (const float*)d_in[2];
    const float* w_attn      = (const float*)d_in[3];
    const float* b_attn      = (const float*)d_in[4];
    const float* w_attn_proj = (const float*)d_in[5];
    const float* b_attn_proj = (const float*)d_in[6];
    const float* ln2_g       = (const float*)d_in[7];
    const float* ln2_b       = (const float*)d_in[8];
    const float* w_fc        = (const float*)d_in[9];
    const float* b_fc        = (const float*)d_in[10];
    const float* w_mlp_proj  = (const float*)d_in[11];
    const float* b_mlp_proj  = (const float*)d_in[12];

    char* ws = (char*)d_ws;
    size_t off = 0;
    auto alloc = [&](size_t n) -> void* {
        off = (off + 255) & ~(size_t)255;
        void* p = ws + off;
        off += n;
        return p;
    };
    bf16* wqkvT  = (bf16*)alloc((size_t)C3 * N_EMBD * 2);
    bf16* wprojT = (bf16*)alloc((size_t)N_EMBD * N_EMBD * 2);
    bf16* wfcT   = (bf16*)alloc((size_t)4 * N_EMBD * N_EMBD * 2);
    bf16* wmlpT  = (bf16*)alloc((size_t)N_EMBD * 4 * N_EMBD * 2);
    bf16* hbuf   = (bf16*)alloc((size_t)ROWS * N_EMBD * 2);
    float* x2    = (float*)alloc((size_t)ROWS * N_EMBD * 4);
    bf16* yb     = (bf16*)alloc((size_t)ROWS * N_EMBD * 2);
    bf16* vtb    = (bf16*)alloc((size_t)BATCH * N_HEAD * 64 * SEQ * 2);
    bf16* big    = (bf16*)alloc((size_t)ROWS * 4 * N_EMBD * 2);
    bf16* qkvb   = big;        // [ROWS, 2304]
    bf16* actb   = big;        // [ROWS, 3072]

    k_transpose_all<<<6912, 256, 0, stream>>>(w_attn, wqkvT, w_attn_proj, wprojT,
                                              w_fc, wfcT, w_mlp_proj, wmlpT);

    k_layernorm<<<ROWS / 4, 256, 0, stream>>>(x, ln1_g, ln1_b, hbuf);
    // qkv: m-fast grid, BK=32 dbuf (32KB LDS, 1 barrier/K-step, stage overlapped)
    k_gemm<128, 32, 0, false, true,  true,  true><<<dim3(ROWS / 128, C3 / 128), 256, 0, stream>>>(
        hbuf, wqkvT,  b_attn,      nullptr, qkvb, ROWS, C3,     N_EMBD);
    k_vtrans<<<dim3(SEQ / 32, BATCH * N_HEAD, 2), 256, 0, stream>>>(qkvb, vtb);
    k_flash<<<768, 256, 0, stream>>>(qkvb, vtb, yb);
    // proj: 64x64 4-wave blocks, 3 blocks/CU
    k_gemm2<<<dim3(ROWS / 64, N_EMBD / 64), 256, 0, stream>>>(
        yb,   wprojT, b_attn_proj, x,       x2,   ROWS, N_EMBD, N_EMBD);
    k_layernorm<<<ROWS / 4, 256, 0, stream>>>(x2, ln2_g, ln2_b, hbuf);
    // fc: m-fast grid, BK=32 dbuf
    k_gemm<128, 32, 1, false, true,  true,  true><<<dim3(ROWS / 128, 3072 / 128), 256, 0, stream>>>(
        hbuf, wfcT,   b_fc,        nullptr, actb, ROWS, 3072,   N_EMBD);
    // mlp: 64x64 4-wave blocks, 3 blocks/CU
    k_gemm2<<<dim3(ROWS / 64, N_EMBD / 64), 256, 0, stream>>>(
        actb, wmlpT,  b_mlp_proj,  x2, (float*)d_out, ROWS, N_EMBD, 3072);
}